// Round 7
// baseline (249.691 us; speedup 1.0000x reference)
//
#include <hip/hip_runtime.h>
#include <stdint.h>
#include <stddef.h>

#define Tdim 4096
#define Hdim 2048

typedef short short8 __attribute__((ext_vector_type(8)));
typedef float floatx4 __attribute__((ext_vector_type(4)));

// RNE fp32 -> bf16 bit pattern
__device__ __forceinline__ unsigned short f2bf(float f) {
  uint32_t u = __float_as_uint(f);
  u += 0x7fffu + ((u >> 16) & 1u);
  return (unsigned short)(u >> 16);
}

__device__ __forceinline__ float bf2f(unsigned short u) {
  return __uint_as_float(((uint32_t)u) << 16);
}

__device__ __forceinline__ float tanh_fast(float z) {
  // tanh(z) = 1 - 2/(exp(2z)+1); safe for all z
  float e = __expf(z + z);
  return 1.0f - __fdividef(2.0f, e + 1.0f);
}

// aligned LDS vector read (forces ds_read_b128)
__device__ __forceinline__ short8 lds_read8(const unsigned short* p) {
  return *(const short8*)__builtin_assume_aligned(p, 16);
}

// ---- fused convert: blocks [0,4096) cast x -> bf16; blocks [4096,5120)
// transpose+cast b (HxH fp32, [k][n]) -> bt bf16 (N x K, [n][k]) ----
__global__ __launch_bounds__(256) void cvt_kernel(const float* __restrict__ x,
                                                  const float* __restrict__ b,
                                                  unsigned short* __restrict__ xbf,
                                                  unsigned short* __restrict__ bt) {
  __shared__ unsigned short tile[64 * 65];
  const int t = threadIdx.x;
  if (blockIdx.x < 4096) {
    size_t i = ((size_t)blockIdx.x * 256 + t) * 8;
    float4 f0 = *(const float4*)(x + i);
    float4 f1 = *(const float4*)(x + i + 4);
    union { unsigned short u[8]; uint4 v; } o;
    o.u[0] = f2bf(f0.x); o.u[1] = f2bf(f0.y); o.u[2] = f2bf(f0.z); o.u[3] = f2bf(f0.w);
    o.u[4] = f2bf(f1.x); o.u[5] = f2bf(f1.y); o.u[6] = f2bf(f1.z); o.u[7] = f2bf(f1.w);
    *(uint4*)(xbf + i) = o.v;
    return;
  }
  const int tb = blockIdx.x - 4096;
  const int bj = tb & 31;  // n block
  const int bi = tb >> 5;  // k block
  {
    const int r0 = t >> 4, c4 = (t & 15) * 4;
#pragma unroll
    for (int p = 0; p < 4; ++p) {
      int r = r0 + p * 16;
      float4 v = *(const float4*)(b + (size_t)(bi * 64 + r) * Hdim + bj * 64 + c4);
      tile[r * 65 + c4 + 0] = f2bf(v.x);
      tile[r * 65 + c4 + 1] = f2bf(v.y);
      tile[r * 65 + c4 + 2] = f2bf(v.z);
      tile[r * 65 + c4 + 3] = f2bf(v.w);
    }
  }
  __syncthreads();
  {
    const int n = t >> 2, kq = (t & 3) * 16;
    union { unsigned short u[16]; uint4 v[2]; } o;
#pragma unroll
    for (int q = 0; q < 16; ++q) o.u[q] = tile[(kq + q) * 65 + n];
    uint4* dst = (uint4*)(bt + (size_t)(bj * 64 + n) * Hdim + bi * 64 + kq);
    dst[0] = o.v[0];
    dst[1] = o.v[1];
  }
}

// ---- GEMM: s(MxN bf16) = A(MxK bf16) * B, B supplied as Bt(NxK bf16) ----
// 128x128 tile, BK=64, 4 waves 2x2 of 64x64 (4x4 frags of 16x16x32 MFMA).
//
// Register-prefetch staging (round 7): issue buffer_load_dwordx4 for tile
// k0+1 into VGPRs BEFORE computing tile k0 from LDS, so the vmcnt drain at
// the post-compute barrier lands after ~600 cyc of MFMA has covered the
// L2/L3 load latency. (Rounds 5/6 used global_load_lds, whose vmcnt(0)
// drain sits at the PRE-compute barrier: ~400-900 cyc of exposed latency
// per k0, MfmaUtil pinned at 28% regardless of resident-block count.)
//
// XOR-swizzled LDS: slot (row, chunk c) holds global chunk (c ^ (row&7));
// fragment reads XOR the same term (round-5: SQ_LDS_BANK_CONFLICT
// 1.26e7 -> 0). Swizzle applied on the global fetch column.
__global__ __launch_bounds__(256) void gemm_bt_kernel(const unsigned short* __restrict__ A,
                                                      const unsigned short* __restrict__ Bt,
                                                      unsigned short* __restrict__ S) {
  __shared__ alignas(16) unsigned short sA[128 * 64];
  __shared__ alignas(16) unsigned short sB[128 * 64];
  const int tid = threadIdx.x;
  const int bn = blockIdx.x, bm = blockIdx.y;
  const int wave = tid >> 6, lane = tid & 63;
  const int wm = (wave >> 1) * 64, wn = (wave & 1) * 64;
  const int l15 = lane & 15, quad = lane >> 4;
  const int l7 = l15 & 7;  // row&7 of every row this lane reads fragments from

  // staging: thread tid owns LDS slot (row=tid>>3 + 32c, chunk=tid&7) and
  // fetches global chunk (tid&7) ^ (row&7); row advances by 32 (0 mod 8)
  // per c, so the XOR term is constant per thread.
  const int swz = ((tid & 7) ^ ((tid >> 3) & 7)) * 8;
  const unsigned short* aSrc = A + ((size_t)(bm * 128 + (tid >> 3)) * Hdim + swz);
  const unsigned short* bSrc = Bt + ((size_t)(bn * 128 + (tid >> 3)) * Hdim + swz);
  unsigned short* aDst = &sA[tid * 8];
  unsigned short* bDst = &sB[tid * 8];

  uint4 ra[4], rb[4];

  // prologue: fetch tile 0 -> regs -> LDS
#pragma unroll
  for (int c = 0; c < 4; ++c) {
    ra[c] = *(const uint4*)(aSrc + (size_t)c * 32 * Hdim);
    rb[c] = *(const uint4*)(bSrc + (size_t)c * 32 * Hdim);
  }
#pragma unroll
  for (int c = 0; c < 4; ++c) {
    *(uint4*)__builtin_assume_aligned(aDst + c * 2048, 16) = ra[c];
    *(uint4*)__builtin_assume_aligned(bDst + c * 2048, 16) = rb[c];
  }
  __syncthreads();

  floatx4 acc[4][4] = {};

  for (int k0 = 64; k0 <= Hdim; k0 += 64) {
    // prefetch next tile into registers (loads in flight during compute)
    if (k0 < Hdim) {
#pragma unroll
      for (int c = 0; c < 4; ++c) {
        ra[c] = *(const uint4*)(aSrc + (size_t)c * 32 * Hdim + k0);
        rb[c] = *(const uint4*)(bSrc + (size_t)c * 32 * Hdim + k0);
      }
    }
    // compute tile k0-64 from LDS
#pragma unroll
    for (int kk = 0; kk < 64; kk += 32) {
      // fragment chunk index = kk/8 + quad, swizzled by row&7 (= l15&7)
      const int coff = (((kk >> 3) + quad) ^ l7) * 8;
      short8 av[4], bv[4];
#pragma unroll
      for (int i = 0; i < 4; ++i)
        av[i] = lds_read8(&sA[(wm + i * 16 + l15) * 64 + coff]);
#pragma unroll
      for (int j = 0; j < 4; ++j)
        bv[j] = lds_read8(&sB[(wn + j * 16 + l15) * 64 + coff]);
#pragma unroll
      for (int i = 0; i < 4; ++i)
#pragma unroll
        for (int j = 0; j < 4; ++j)
          acc[i][j] = __builtin_amdgcn_mfma_f32_16x16x32_bf16(av[i], bv[j], acc[i][j], 0, 0, 0);
    }
    __syncthreads();  // ds_reads of old tile done; prefetch loads drained here (post-compute)
    if (k0 < Hdim) {
#pragma unroll
      for (int c = 0; c < 4; ++c) {
        *(uint4*)__builtin_assume_aligned(aDst + c * 2048, 16) = ra[c];
        *(uint4*)__builtin_assume_aligned(bDst + c * 2048, 16) = rb[c];
      }
      __syncthreads();
    }
  }

  // C/D layout: col = lane&15, row = quad*4 + r (m89/m91-verified); bf16 out
  const int row0 = bm * 128 + wm + quad * 4;
  const int col0 = bn * 128 + wn + l15;
#pragma unroll
  for (int i = 0; i < 4; ++i)
#pragma unroll
    for (int j = 0; j < 4; ++j)
#pragma unroll
      for (int r = 0; r < 4; ++r)
        S[(size_t)(row0 + i * 16 + r) * Hdim + (col0 + j * 16)] = f2bf(acc[i][j][r]);
}

// ---- windowed parallel "scan": |a| <= 0.03125 so influence of h_{t-8} < 1e-12.
// s is bf16 (rounding adds ~1.6e-3 rms, contracted by tanh'/|a|). ----
__global__ __launch_bounds__(256) void scan_kernel(const unsigned short* __restrict__ S,
                                                   const float* __restrict__ a,
                                                   float* __restrict__ out) {
  const int j = blockIdx.x * 256 + threadIdx.x;  // column
  const int t0 = blockIdx.y * 32;                // output chunk start
  const float aj = a[j];
  float h = 0.0f;
  int ts = t0 - 8;
  if (ts < 0) ts = 0;
  for (int t = ts; t < t0; ++t)  // warm-up window (exact for t0==0)
    h = tanh_fast(fmaf(aj, h, bf2f(S[(size_t)t * Hdim + j])));
#pragma unroll
  for (int t = t0; t < t0 + 32; ++t) {
    size_t idx = (size_t)t * Hdim + j;
    h = tanh_fast(fmaf(aj, h, bf2f(S[idx])));
    out[idx] = h;
  }
}

extern "C" void kernel_launch(void* const* d_in, const int* in_sizes, int n_in,
                              void* d_out, int out_size, void* d_ws, size_t ws_size,
                              hipStream_t stream) {
  const float* x = (const float*)d_in[0];
  const float* a = (const float*)d_in[1];
  const float* b = (const float*)d_in[2];
  float* out = (float*)d_out;

  unsigned short* ws = (unsigned short*)d_ws;
  unsigned short* s = ws;                                   // 16.8 MB (bf16)
  unsigned short* xbf = s + (size_t)Tdim * Hdim;            // 16.8 MB
  unsigned short* btb = xbf + (size_t)Tdim * Hdim;          // 8.4 MB

  hipLaunchKernelGGL(cvt_kernel, dim3(4096 + (Hdim / 64) * (Hdim / 64)), dim3(256), 0, stream,
                     x, b, xbf, btb);
  hipLaunchKernelGGL(gemm_bt_kernel, dim3(Hdim / 128, Tdim / 128), dim3(256), 0, stream,
                     xbf, btb, s);
  hipLaunchKernelGGL(scan_kernel, dim3(Hdim / 256, Tdim / 32), dim3(256), 0, stream,
                     s, a, out);
}

// Round 8
// 145.800 us; speedup vs baseline: 1.7126x; 1.7126x over previous
//
#include <hip/hip_runtime.h>
#include <stdint.h>
#include <stddef.h>

#define Tdim 4096
#define Hdim 2048

typedef short short8 __attribute__((ext_vector_type(8)));
typedef float floatx4 __attribute__((ext_vector_type(4)));

// RNE fp32 -> bf16 bit pattern
__device__ __forceinline__ unsigned short f2bf(float f) {
  uint32_t u = __float_as_uint(f);
  u += 0x7fffu + ((u >> 16) & 1u);
  return (unsigned short)(u >> 16);
}

// async global->LDS, 16B per lane. LDS dest is wave-uniform base + lane*16.
__device__ __forceinline__ void load_lds16(const void* g, void* l) {
  __builtin_amdgcn_global_load_lds(
      (__attribute__((address_space(1))) unsigned int*)(uintptr_t)g,
      (__attribute__((address_space(3))) unsigned int*)l,
      16, 0, 0);
}

__device__ __forceinline__ float tanh_fast(float z) {
  // tanh(z) = 1 - 2/(exp(2z)+1); safe for all z
  float e = __expf(z + z);
  return 1.0f - __fdividef(2.0f, e + 1.0f);
}

// aligned LDS vector read (forces ds_read_b128)
__device__ __forceinline__ short8 lds_read8(const unsigned short* p) {
  return *(const short8*)__builtin_assume_aligned(p, 16);
}

// ---- fused convert: blocks [0,4096) cast x -> bf16; blocks [4096,5120)
// transpose+cast b (HxH fp32, [k][n]) -> bt bf16 (N x K, [n][k]) ----
__global__ __launch_bounds__(256) void cvt_kernel(const float* __restrict__ x,
                                                  const float* __restrict__ b,
                                                  unsigned short* __restrict__ xbf,
                                                  unsigned short* __restrict__ bt) {
  __shared__ unsigned short tile[64 * 65];
  const int t = threadIdx.x;
  if (blockIdx.x < 4096) {
    size_t i = ((size_t)blockIdx.x * 256 + t) * 8;
    float4 f0 = *(const float4*)(x + i);
    float4 f1 = *(const float4*)(x + i + 4);
    union { unsigned short u[8]; uint4 v; } o;
    o.u[0] = f2bf(f0.x); o.u[1] = f2bf(f0.y); o.u[2] = f2bf(f0.z); o.u[3] = f2bf(f0.w);
    o.u[4] = f2bf(f1.x); o.u[5] = f2bf(f1.y); o.u[6] = f2bf(f1.z); o.u[7] = f2bf(f1.w);
    *(uint4*)(xbf + i) = o.v;
    return;
  }
  const int tb = blockIdx.x - 4096;
  const int bj = tb & 31;  // n block
  const int bi = tb >> 5;  // k block
  {
    const int r0 = t >> 4, c4 = (t & 15) * 4;
#pragma unroll
    for (int p = 0; p < 4; ++p) {
      int r = r0 + p * 16;
      float4 v = *(const float4*)(b + (size_t)(bi * 64 + r) * Hdim + bj * 64 + c4);
      tile[r * 65 + c4 + 0] = f2bf(v.x);
      tile[r * 65 + c4 + 1] = f2bf(v.y);
      tile[r * 65 + c4 + 2] = f2bf(v.z);
      tile[r * 65 + c4 + 3] = f2bf(v.w);
    }
  }
  __syncthreads();
  {
    const int n = t >> 2, kq = (t & 3) * 16;
    union { unsigned short u[16]; uint4 v[2]; } o;
#pragma unroll
    for (int q = 0; q < 16; ++q) o.u[q] = tile[(kq + q) * 65 + n];
    uint4* dst = (uint4*)(bt + (size_t)(bj * 64 + n) * Hdim + bi * 64 + kq);
    dst[0] = o.v[0];
    dst[1] = o.v[1];
  }
}

// ---- GEMM (s = x @ b) with fused windowed-scan epilogue ----
// 128x128 tile, BK=64, 4 waves 2x2 of 64x64 (4x4 frags of 16x16x32 MFMA).
// K-loop = round-5's plateau kernel (global_load_lds width-16, XOR-swizzled
// LDS: slot (row, chunk c) holds global chunk c^(row&7); swizzle applied on
// the global fetch column so the wave-uniform contiguous global_load_lds
// dest is preserved; fragment reads XOR the same term -> conflicts == 0).
// Warm rows: 8 extra A rows (t0-8..t0-1) so the scan warms up in-block
// (|a| <= 0.03125 -> influence of h_{t-8} < 1e-12). Warm frag read + MFMA
// gated to waves 0,1 only (round-3 let all 4 waves read it).
// Epilogue: acc -> s_tile (136x129 fp32, one-stage; 68.5 KB LDS = 2 blocks/CU
// which equals the grid-forced residency, so no occupancy cost) -> 256
// threads scan 128 cols x 2 half-chunks -> out. No s buffer in HBM at all
// (-33.5 MB round-trip, -1 dispatch vs round 5).
__global__ __launch_bounds__(256) void gemm_scan_kernel(const unsigned short* __restrict__ A,
                                                        const unsigned short* __restrict__ Bt,
                                                        const float* __restrict__ a_mat,
                                                        float* __restrict__ out) {
  // alignas(16) is REQUIRED: union alignment is otherwise 4 and short8 LDS
  // reads split into 4x ds_read_b32 with 16-way conflicts (round-2: 263 us).
  __shared__ alignas(16) union SM {
    struct {
      unsigned short sA[128 * 64];
      unsigned short sB[128 * 64];
      unsigned short sAw[8 * 64];
    } st;                      // 33.25 KB
    float s_tile[136 * 129];   // 68.5 KB; [row][col], pad 129
  } sm;

  const int tid = threadIdx.x;
  const int bn = blockIdx.x, bm = blockIdx.y;
  const int wave = tid >> 6, lane = tid & 63;
  const int wm = (wave >> 1) * 64, wn = (wave & 1) * 64;
  const int l15 = lane & 15, quad = lane >> 4;
  const int l7 = l15 & 7;  // row&7 of the rows this lane reads fragments from

  // staging: thread tid fills LDS slot (row=tid>>3 + 32c, chunk=tid&7) and
  // fetches global chunk (tid&7)^(row&7); row advances by 32 (0 mod 8) per
  // c-chunk, so the XOR term is constant per thread.
  const int swz = ((tid & 7) ^ ((tid >> 3) & 7)) * 8;
  const unsigned short* aSrc = A + ((size_t)(bm * 128 + (tid >> 3)) * Hdim + swz);
  const unsigned short* bSrc = Bt + ((size_t)(bn * 128 + (tid >> 3)) * Hdim + swz);
  // warm rows staged by wave 3: lane -> row=lane>>3 (8 rows), chunk=lane&7
  const int tw0 = (bm > 0) ? bm * 128 - 8 : 0;  // clamp keeps address valid; bm==0 warm unused
  const int wswz = ((lane & 7) ^ ((lane >> 3) & 7)) * 8;
  const unsigned short* wSrc = A + ((size_t)(tw0 + (lane >> 3)) * Hdim + wswz);
  unsigned short* aDst = &sm.st.sA[tid * 8];
  unsigned short* bDst = &sm.st.sB[tid * 8];
  unsigned short* wDst = &sm.st.sAw[lane * 8];

  floatx4 acc[4][4] = {};
  floatx4 accw[4] = {};

  for (int k0 = 0; k0 < Hdim; k0 += 64) {
#pragma unroll
    for (int c = 0; c < 4; ++c)
      load_lds16(aSrc + (size_t)c * 32 * Hdim + k0, aDst + c * 2048);
#pragma unroll
    for (int c = 0; c < 4; ++c)
      load_lds16(bSrc + (size_t)c * 32 * Hdim + k0, bDst + c * 2048);
    if (wave == 3) load_lds16(wSrc + k0, wDst);
    __syncthreads();
#pragma unroll
    for (int kk = 0; kk < 64; kk += 32) {
      // fragment chunk index = kk/8 + quad, swizzled by row&7 (= l15&7)
      const int coff = (((kk >> 3) + quad) ^ l7) * 8;
      short8 av[4], bv[4];
#pragma unroll
      for (int i = 0; i < 4; ++i)
        av[i] = lds_read8(&sm.st.sA[(wm + i * 16 + l15) * 64 + coff]);
#pragma unroll
      for (int j = 0; j < 4; ++j)
        bv[j] = lds_read8(&sm.st.sB[(wn + j * 16 + l15) * 64 + coff]);
#pragma unroll
      for (int i = 0; i < 4; ++i)
#pragma unroll
        for (int j = 0; j < 4; ++j)
          acc[i][j] = __builtin_amdgcn_mfma_f32_16x16x32_bf16(av[i], bv[j], acc[i][j], 0, 0, 0);
      if (wave < 2) {  // warm rows: frag read + MFMA on waves 0,1 only
        short8 aw = lds_read8(&sm.st.sAw[l7 * 64 + coff]);
#pragma unroll
        for (int j = 0; j < 4; ++j)
          accw[j] = __builtin_amdgcn_mfma_f32_16x16x32_bf16(aw, bv[j], accw[j], 0, 0, 0);
      }
    }
    __syncthreads();
  }

  // ---- epilogue: registers -> s_tile (C/D layout: col=lane&15, row=quad*4+r) ----
  if (wave < 2 && quad < 2) {  // warm rows idx 0..7 (valid m = 0..7 only)
#pragma unroll
    for (int j = 0; j < 4; ++j)
#pragma unroll
      for (int r = 0; r < 4; ++r)
        sm.s_tile[(quad * 4 + r) * 129 + wn + j * 16 + l15] = accw[j][r];
  }
#pragma unroll
  for (int i = 0; i < 4; ++i)
#pragma unroll
    for (int j = 0; j < 4; ++j)
#pragma unroll
      for (int r = 0; r < 4; ++r)
        sm.s_tile[(8 + wm + i * 16 + quad * 4 + r) * 129 + wn + j * 16 + l15] = acc[i][j][r];
  __syncthreads();

  // ---- windowed scan: 256 threads = 128 cols x 2 half-chunks of 64 rows ----
  const int col = tid & 127;
  const int half = tid >> 7;
  const float aj = a_mat[bn * 128 + col];
  float h = 0.0f;
  const int row0 = 8 + half * 64;
  if (!(bm == 0 && half == 0)) {
#pragma unroll
    for (int r = row0 - 8; r < row0; ++r)  // warm-up (discarded outputs)
      h = tanh_fast(fmaf(aj, h, sm.s_tile[r * 129 + col]));
  }
  const size_t gbase = (size_t)(bm * 128 + half * 64) * Hdim + bn * 128 + col;
#pragma unroll 4
  for (int r2 = 0; r2 < 64; ++r2) {
    h = tanh_fast(fmaf(aj, h, sm.s_tile[(row0 + r2) * 129 + col]));
    out[gbase + (size_t)r2 * Hdim] = h;
  }
}

extern "C" void kernel_launch(void* const* d_in, const int* in_sizes, int n_in,
                              void* d_out, int out_size, void* d_ws, size_t ws_size,
                              hipStream_t stream) {
  const float* x = (const float*)d_in[0];
  const float* a = (const float*)d_in[1];
  const float* b = (const float*)d_in[2];
  float* out = (float*)d_out;

  unsigned short* ws = (unsigned short*)d_ws;
  unsigned short* xbf = ws;                                 // 16.8 MB
  unsigned short* btb = xbf + (size_t)Tdim * Hdim;          // 8.4 MB

  hipLaunchKernelGGL(cvt_kernel, dim3(4096 + (Hdim / 64) * (Hdim / 64)), dim3(256), 0, stream,
                     x, b, xbf, btb);
  hipLaunchKernelGGL(gemm_scan_kernel, dim3(Hdim / 128, Tdim / 128), dim3(256), 0, stream,
                     xbf, btb, a, out);
}

// Round 9
// 145.292 us; speedup vs baseline: 1.7185x; 1.0035x over previous
//
#include <hip/hip_runtime.h>
#include <stdint.h>
#include <stddef.h>

#define Tdim 4096
#define Hdim 2048

typedef short short8 __attribute__((ext_vector_type(8)));
typedef float floatx4 __attribute__((ext_vector_type(4)));

// RNE fp32 -> bf16 bit pattern
__device__ __forceinline__ unsigned short f2bf(float f) {
  uint32_t u = __float_as_uint(f);
  u += 0x7fffu + ((u >> 16) & 1u);
  return (unsigned short)(u >> 16);
}

// async global->LDS, 16B per lane. LDS dest is wave-uniform base + lane*16.
__device__ __forceinline__ void load_lds16(const void* g, void* l) {
  __builtin_amdgcn_global_load_lds(
      (__attribute__((address_space(1))) unsigned int*)(uintptr_t)g,
      (__attribute__((address_space(3))) unsigned int*)l,
      16, 0, 0);
}

__device__ __forceinline__ float tanh_fast(float z) {
  // tanh(z) = 1 - 2/(exp(2z)+1); safe for all z
  float e = __expf(z + z);
  return 1.0f - __fdividef(2.0f, e + 1.0f);
}

// aligned LDS vector read (forces ds_read_b128)
__device__ __forceinline__ short8 lds_read8(const unsigned short* p) {
  return *(const short8*)__builtin_assume_aligned(p, 16);
}

// ---- fused convert: blocks [0,4096) cast x -> bf16; blocks [4096,5120)
// transpose+cast b (HxH fp32, [k][n]) -> bt bf16 (N x K, [n][k]) ----
__global__ __launch_bounds__(256) void cvt_kernel(const float* __restrict__ x,
                                                  const float* __restrict__ b,
                                                  unsigned short* __restrict__ xbf,
                                                  unsigned short* __restrict__ bt) {
  __shared__ unsigned short tile[64 * 65];
  const int t = threadIdx.x;
  if (blockIdx.x < 4096) {
    size_t i = ((size_t)blockIdx.x * 256 + t) * 8;
    float4 f0 = *(const float4*)(x + i);
    float4 f1 = *(const float4*)(x + i + 4);
    union { unsigned short u[8]; uint4 v; } o;
    o.u[0] = f2bf(f0.x); o.u[1] = f2bf(f0.y); o.u[2] = f2bf(f0.z); o.u[3] = f2bf(f0.w);
    o.u[4] = f2bf(f1.x); o.u[5] = f2bf(f1.y); o.u[6] = f2bf(f1.z); o.u[7] = f2bf(f1.w);
    *(uint4*)(xbf + i) = o.v;
    return;
  }
  const int tb = blockIdx.x - 4096;
  const int bj = tb & 31;  // n block
  const int bi = tb >> 5;  // k block
  {
    const int r0 = t >> 4, c4 = (t & 15) * 4;
#pragma unroll
    for (int p = 0; p < 4; ++p) {
      int r = r0 + p * 16;
      float4 v = *(const float4*)(b + (size_t)(bi * 64 + r) * Hdim + bj * 64 + c4);
      tile[r * 65 + c4 + 0] = f2bf(v.x);
      tile[r * 65 + c4 + 1] = f2bf(v.y);
      tile[r * 65 + c4 + 2] = f2bf(v.z);
      tile[r * 65 + c4 + 3] = f2bf(v.w);
    }
  }
  __syncthreads();
  {
    const int n = t >> 2, kq = (t & 3) * 16;
    union { unsigned short u[16]; uint4 v[2]; } o;
#pragma unroll
    for (int q = 0; q < 16; ++q) o.u[q] = tile[(kq + q) * 65 + n];
    uint4* dst = (uint4*)(bt + (size_t)(bj * 64 + n) * Hdim + bi * 64 + kq);
    dst[0] = o.v[0];
    dst[1] = o.v[1];
  }
}

// ---- GEMM (s = x @ b) with fused windowed-scan epilogue ----
// 128x128 tile, BK=64, 4 waves 2x2 of 64x64 (4x4 frags of 16x16x32 MFMA).
// K-loop: global_load_lds width-16, XOR-swizzled LDS (slot (row, chunk c)
// holds global chunk c^(row&7); swizzle applied on the global fetch column;
// fragment reads XOR the same term -> SQ_LDS_BANK_CONFLICT ~0).
//
// XCD swizzle (round 9): grid is (bm=32, bn=16) with bm FASTEST so
// XCD = block%8 = bm%8. Each XCD's 64 resident blocks then cover only
// 4 bm strips -> A working set 4x512KB = 2MB, resident in the XCD's 4MB L2
// and reused 16x; B slabs reused 4x. (Round-8 mapping bn%8 streamed all
// 16.8MB of A through every XCD's L2 from L3 -> staging drain ~L3 latency,
// MfmaUtil pinned 27%.)
//
// Warm rows: 8 extra A rows (t0-8..t0-1) so the scan warms up in-block
// (|a| <= 0.03125 -> influence of h_{t-8} < 1e-12); warm frag+MFMA on
// waves 0,1 only. Epilogue: acc -> s_tile (136x129 fp32, 68.5KB LDS =
// 2 blocks/CU = grid-forced residency anyway) -> 256 threads scan
// 128 cols x 2 half-chunks -> out. No s buffer in HBM.
__global__ __launch_bounds__(256) void gemm_scan_kernel(const unsigned short* __restrict__ A,
                                                        const unsigned short* __restrict__ Bt,
                                                        const float* __restrict__ a_mat,
                                                        float* __restrict__ out) {
  // alignas(16) REQUIRED: otherwise union alignment is 4 and short8 LDS
  // reads split into 4x ds_read_b32 with 16-way conflicts (round-2: 263 us).
  __shared__ alignas(16) union SM {
    struct {
      unsigned short sA[128 * 64];
      unsigned short sB[128 * 64];
      unsigned short sAw[8 * 64];
    } st;                      // 33.25 KB
    float s_tile[136 * 129];   // 68.5 KB; [row][col], pad 129
  } sm;

  const int tid = threadIdx.x;
  const int bm = blockIdx.x, bn = blockIdx.y;  // bm fastest -> XCD = bm%8
  const int wave = tid >> 6, lane = tid & 63;
  const int wm = (wave >> 1) * 64, wn = (wave & 1) * 64;
  const int l15 = lane & 15, quad = lane >> 4;
  const int l7 = l15 & 7;  // row&7 of the rows this lane reads fragments from

  // staging: thread tid fills LDS slot (row=tid>>3 + 32c, chunk=tid&7) and
  // fetches global chunk (tid&7)^(row&7); row advances by 32 (0 mod 8) per
  // c-chunk, so the XOR term is constant per thread.
  const int swz = ((tid & 7) ^ ((tid >> 3) & 7)) * 8;
  const unsigned short* aSrc = A + ((size_t)(bm * 128 + (tid >> 3)) * Hdim + swz);
  const unsigned short* bSrc = Bt + ((size_t)(bn * 128 + (tid >> 3)) * Hdim + swz);
  // warm rows staged by wave 3: lane -> row=lane>>3 (8 rows), chunk=lane&7
  const int tw0 = (bm > 0) ? bm * 128 - 8 : 0;  // clamp keeps address valid; bm==0 warm unused
  const int wswz = ((lane & 7) ^ ((lane >> 3) & 7)) * 8;
  const unsigned short* wSrc = A + ((size_t)(tw0 + (lane >> 3)) * Hdim + wswz);
  unsigned short* aDst = &sm.st.sA[tid * 8];
  unsigned short* bDst = &sm.st.sB[tid * 8];
  unsigned short* wDst = &sm.st.sAw[lane * 8];

  floatx4 acc[4][4] = {};
  floatx4 accw[4] = {};

  for (int k0 = 0; k0 < Hdim; k0 += 64) {
#pragma unroll
    for (int c = 0; c < 4; ++c)
      load_lds16(aSrc + (size_t)c * 32 * Hdim + k0, aDst + c * 2048);
#pragma unroll
    for (int c = 0; c < 4; ++c)
      load_lds16(bSrc + (size_t)c * 32 * Hdim + k0, bDst + c * 2048);
    if (wave == 3) load_lds16(wSrc + k0, wDst);
    __syncthreads();
#pragma unroll
    for (int kk = 0; kk < 64; kk += 32) {
      // fragment chunk index = kk/8 + quad, swizzled by row&7 (= l15&7)
      const int coff = (((kk >> 3) + quad) ^ l7) * 8;
      short8 av[4], bv[4];
#pragma unroll
      for (int i = 0; i < 4; ++i)
        av[i] = lds_read8(&sm.st.sA[(wm + i * 16 + l15) * 64 + coff]);
#pragma unroll
      for (int j = 0; j < 4; ++j)
        bv[j] = lds_read8(&sm.st.sB[(wn + j * 16 + l15) * 64 + coff]);
#pragma unroll
      for (int i = 0; i < 4; ++i)
#pragma unroll
        for (int j = 0; j < 4; ++j)
          acc[i][j] = __builtin_amdgcn_mfma_f32_16x16x32_bf16(av[i], bv[j], acc[i][j], 0, 0, 0);
      if (wave < 2) {  // warm rows: frag read + MFMA on waves 0,1 only
        short8 aw = lds_read8(&sm.st.sAw[l7 * 64 + coff]);
#pragma unroll
        for (int j = 0; j < 4; ++j)
          accw[j] = __builtin_amdgcn_mfma_f32_16x16x32_bf16(aw, bv[j], accw[j], 0, 0, 0);
      }
    }
    __syncthreads();
  }

  // ---- epilogue: registers -> s_tile (C/D layout: col=lane&15, row=quad*4+r) ----
  if (wave < 2 && quad < 2) {  // warm rows idx 0..7 (valid m = 0..7 only)
#pragma unroll
    for (int j = 0; j < 4; ++j)
#pragma unroll
      for (int r = 0; r < 4; ++r)
        sm.s_tile[(quad * 4 + r) * 129 + wn + j * 16 + l15] = accw[j][r];
  }
#pragma unroll
  for (int i = 0; i < 4; ++i)
#pragma unroll
    for (int j = 0; j < 4; ++j)
#pragma unroll
      for (int r = 0; r < 4; ++r)
        sm.s_tile[(8 + wm + i * 16 + quad * 4 + r) * 129 + wn + j * 16 + l15] = acc[i][j][r];
  __syncthreads();

  // ---- windowed scan: 256 threads = 128 cols x 2 half-chunks of 64 rows ----
  const int col = tid & 127;
  const int half = tid >> 7;
  const float aj = a_mat[bn * 128 + col];
  float h = 0.0f;
  const int row0 = 8 + half * 64;
  if (!(bm == 0 && half == 0)) {
#pragma unroll
    for (int r = row0 - 8; r < row0; ++r)  // warm-up (discarded outputs)
      h = tanh_fast(fmaf(aj, h, sm.s_tile[r * 129 + col]));
  }
  const size_t gbase = (size_t)(bm * 128 + half * 64) * Hdim + bn * 128 + col;
#pragma unroll 4
  for (int r2 = 0; r2 < 64; ++r2) {
    h = tanh_fast(fmaf(aj, h, sm.s_tile[(row0 + r2) * 129 + col]));
    out[gbase + (size_t)r2 * Hdim] = h;
  }
}

extern "C" void kernel_launch(void* const* d_in, const int* in_sizes, int n_in,
                              void* d_out, int out_size, void* d_ws, size_t ws_size,
                              hipStream_t stream) {
  const float* x = (const float*)d_in[0];
  const float* a = (const float*)d_in[1];
  const float* b = (const float*)d_in[2];
  float* out = (float*)d_out;

  unsigned short* ws = (unsigned short*)d_ws;
  unsigned short* xbf = ws;                                 // 16.8 MB
  unsigned short* btb = xbf + (size_t)Tdim * Hdim;          // 8.4 MB

  hipLaunchKernelGGL(cvt_kernel, dim3(4096 + (Hdim / 64) * (Hdim / 64)), dim3(256), 0, stream,
                     x, b, xbf, btb);
  // grid: x = bm (32, fastest -> XCD = bm%8), y = bn (16)
  hipLaunchKernelGGL(gemm_scan_kernel, dim3(Tdim / 128, Hdim / 128), dim3(256), 0, stream,
                     xbf, btb, a, out);
}

// Round 10
// 143.435 us; speedup vs baseline: 1.7408x; 1.0129x over previous
//
#include <hip/hip_runtime.h>
#include <stdint.h>
#include <stddef.h>

#define Tdim 4096
#define Hdim 2048

typedef short short8 __attribute__((ext_vector_type(8)));
typedef float floatx4 __attribute__((ext_vector_type(4)));

// RNE fp32 -> bf16 bit pattern
__device__ __forceinline__ unsigned short f2bf(float f) {
  uint32_t u = __float_as_uint(f);
  u += 0x7fffu + ((u >> 16) & 1u);
  return (unsigned short)(u >> 16);
}

// async global->LDS, 16B per lane. LDS dest is wave-uniform base + lane*16.
__device__ __forceinline__ void load_lds16(const void* g, void* l) {
  __builtin_amdgcn_global_load_lds(
      (__attribute__((address_space(1))) unsigned int*)(uintptr_t)g,
      (__attribute__((address_space(3))) unsigned int*)l,
      16, 0, 0);
}

__device__ __forceinline__ float tanh_fast(float z) {
  // tanh(z) = 1 - 2/(exp(2z)+1); safe for all z
  float e = __expf(z + z);
  return 1.0f - __fdividef(2.0f, e + 1.0f);
}

// aligned LDS vector read (forces ds_read_b128)
__device__ __forceinline__ short8 lds_read8(const unsigned short* p) {
  return *(const short8*)__builtin_assume_aligned(p, 16);
}

// ---- fused convert: blocks [0,4096) cast x -> bf16; blocks [4096,5120)
// transpose+cast b (HxH fp32, [k][n]) -> bt bf16 (N x K, [n][k]) ----
__global__ __launch_bounds__(256) void cvt_kernel(const float* __restrict__ x,
                                                  const float* __restrict__ b,
                                                  unsigned short* __restrict__ xbf,
                                                  unsigned short* __restrict__ bt) {
  __shared__ unsigned short tile[64 * 65];
  const int t = threadIdx.x;
  if (blockIdx.x < 4096) {
    size_t i = ((size_t)blockIdx.x * 256 + t) * 8;
    float4 f0 = *(const float4*)(x + i);
    float4 f1 = *(const float4*)(x + i + 4);
    union { unsigned short u[8]; uint4 v; } o;
    o.u[0] = f2bf(f0.x); o.u[1] = f2bf(f0.y); o.u[2] = f2bf(f0.z); o.u[3] = f2bf(f0.w);
    o.u[4] = f2bf(f1.x); o.u[5] = f2bf(f1.y); o.u[6] = f2bf(f1.z); o.u[7] = f2bf(f1.w);
    *(uint4*)(xbf + i) = o.v;
    return;
  }
  const int tb = blockIdx.x - 4096;
  const int bj = tb & 31;  // n block
  const int bi = tb >> 5;  // k block
  {
    const int r0 = t >> 4, c4 = (t & 15) * 4;
#pragma unroll
    for (int p = 0; p < 4; ++p) {
      int r = r0 + p * 16;
      float4 v = *(const float4*)(b + (size_t)(bi * 64 + r) * Hdim + bj * 64 + c4);
      tile[r * 65 + c4 + 0] = f2bf(v.x);
      tile[r * 65 + c4 + 1] = f2bf(v.y);
      tile[r * 65 + c4 + 2] = f2bf(v.z);
      tile[r * 65 + c4 + 3] = f2bf(v.w);
    }
  }
  __syncthreads();
  {
    const int n = t >> 2, kq = (t & 3) * 16;
    union { unsigned short u[16]; uint4 v[2]; } o;
#pragma unroll
    for (int q = 0; q < 16; ++q) o.u[q] = tile[(kq + q) * 65 + n];
    uint4* dst = (uint4*)(bt + (size_t)(bj * 64 + n) * Hdim + bi * 64 + kq);
    dst[0] = o.v[0];
    dst[1] = o.v[1];
  }
}

// ---- GEMM (s = x @ b) with fused windowed-scan epilogue ----
// 128x128 tile, BK=128 (round 10), 4 waves 2x2 of 64x64 (4x4 frags of
// 16x16x32 MFMA). BK=128 halves the K-loop barrier/drain count (32 -> 16)
// at zero occupancy cost: LDS is dominated by the 68.5KB s_tile union and
// the grid forces 2 blocks/CU anyway (m132's BK=128 regression was an
// occupancy loss that doesn't apply here).
//
// K-loop: global_load_lds width-16, XOR-swizzled LDS (slot (row, chunk c)
// holds global chunk c with low 3 bits XORed by row&7; swizzle applied on
// the global fetch column; fragment reads XOR the same term ->
// SQ_LDS_BANK_CONFLICT ~0).
//
// XCD swizzle: grid (bm=32 fastest, bn=16) so XCD = bm%8; each XCD's A
// working set is 2MB (L2-resident, 16x reuse) -> FETCH 69.7 -> 41.5 MB (r9).
//
// Warm rows: 8 extra A rows (t0-8..t0-1) so the scan warms up in-block
// (|a| <= 0.03125 -> influence of h_{t-8} < 1e-12); warm frag+MFMA on
// waves 0,1 only. Epilogue: acc -> s_tile (136x129 fp32) -> 256 threads
// scan 128 cols x 2 half-chunks -> out. No s buffer in HBM.
__global__ __launch_bounds__(256) void gemm_scan_kernel(const unsigned short* __restrict__ A,
                                                        const unsigned short* __restrict__ Bt,
                                                        const float* __restrict__ a_mat,
                                                        float* __restrict__ out) {
  // alignas(16) REQUIRED: otherwise union alignment is 4 and short8 LDS
  // reads split into 4x ds_read_b32 with 16-way conflicts (round-2: 263 us).
  __shared__ alignas(16) union SM {
    struct {
      unsigned short sA[128 * 128];   // 32 KB
      unsigned short sB[128 * 128];   // 32 KB
      unsigned short sAw[8 * 128];    // 2 KB
    } st;                      // 66 KB
    float s_tile[136 * 129];   // 68.5 KB; [row][col], pad 129
  } sm;

  const int tid = threadIdx.x;
  const int bm = blockIdx.x, bn = blockIdx.y;  // bm fastest -> XCD = bm%8
  const int wave = tid >> 6, lane = tid & 63;
  const int wm = (wave >> 1) * 64, wn = (wave & 1) * 64;
  const int l15 = lane & 15, quad = lane >> 4;
  const int l7 = l15 & 7;  // row&7 of the rows this lane reads fragments from

  // staging (BK=128 = 16 chunks of 8 bf16 per row): thread tid fills LDS
  // slot (row = 16c + (tid>>4), chunk = tid&15) = &s[c*2048 + tid*8];
  // fetches global chunk with low-3-bits XOR by row&7. Rows advance 16 per
  // issue (0 mod 8) so the XOR term is constant per thread.
  const int swz = ((tid & 15) ^ ((tid >> 4) & 7)) * 8;
  const unsigned short* aSrc = A + ((size_t)(bm * 128 + (tid >> 4)) * Hdim + swz);
  const unsigned short* bSrc = Bt + ((size_t)(bn * 128 + (tid >> 4)) * Hdim + swz);
  // warm rows staged by wave 3 in two issues of 4 rows (4 !≡ 0 mod 8, so
  // each issue has its own swizzle term)
  const int tw0 = (bm > 0) ? bm * 128 - 8 : 0;  // clamp keeps address valid; bm==0 warm unused
  const int wrow0 = lane >> 4;  // 0..3
  const unsigned short* wSrc0 =
      A + ((size_t)(tw0 + wrow0) * Hdim + ((lane & 15) ^ (wrow0 & 7)) * 8);
  const unsigned short* wSrc1 =
      A + ((size_t)(tw0 + 4 + wrow0) * Hdim + ((lane & 15) ^ ((4 + wrow0) & 7)) * 8);
  unsigned short* aDst = &sm.st.sA[tid * 8];
  unsigned short* bDst = &sm.st.sB[tid * 8];
  unsigned short* wDst = &sm.st.sAw[lane * 8];

  floatx4 acc[4][4] = {};
  floatx4 accw[4] = {};

  for (int k0 = 0; k0 < Hdim; k0 += 128) {
#pragma unroll
    for (int c = 0; c < 8; ++c)
      load_lds16(aSrc + (size_t)c * 16 * Hdim + k0, aDst + c * 2048);
#pragma unroll
    for (int c = 0; c < 8; ++c)
      load_lds16(bSrc + (size_t)c * 16 * Hdim + k0, bDst + c * 2048);
    if (wave == 3) {
      load_lds16(wSrc0 + k0, wDst);
      load_lds16(wSrc1 + k0, wDst + 512);
    }
    __syncthreads();
#pragma unroll
    for (int kk = 0; kk < 128; kk += 32) {
      // fragment chunk index = kk/8 + quad (0..15), low 3 bits XORed by l7
      const int coff = (((kk >> 3) + quad) ^ l7) * 8;
      short8 av[4], bv[4];
#pragma unroll
      for (int i = 0; i < 4; ++i)
        av[i] = lds_read8(&sm.st.sA[(wm + i * 16 + l15) * 128 + coff]);
#pragma unroll
      for (int j = 0; j < 4; ++j)
        bv[j] = lds_read8(&sm.st.sB[(wn + j * 16 + l15) * 128 + coff]);
#pragma unroll
      for (int i = 0; i < 4; ++i)
#pragma unroll
        for (int j = 0; j < 4; ++j)
          acc[i][j] = __builtin_amdgcn_mfma_f32_16x16x32_bf16(av[i], bv[j], acc[i][j], 0, 0, 0);
      if (wave < 2) {  // warm rows: frag read + MFMA on waves 0,1 only
        short8 aw = lds_read8(&sm.st.sAw[l7 * 128 + coff]);
#pragma unroll
        for (int j = 0; j < 4; ++j)
          accw[j] = __builtin_amdgcn_mfma_f32_16x16x32_bf16(aw, bv[j], accw[j], 0, 0, 0);
      }
    }
    __syncthreads();
  }

  // ---- epilogue: registers -> s_tile (C/D layout: col=lane&15, row=quad*4+r) ----
  if (wave < 2 && quad < 2) {  // warm rows idx 0..7 (valid m = 0..7 only)
#pragma unroll
    for (int j = 0; j < 4; ++j)
#pragma unroll
      for (int r = 0; r < 4; ++r)
        sm.s_tile[(quad * 4 + r) * 129 + wn + j * 16 + l15] = accw[j][r];
  }
#pragma unroll
  for (int i = 0; i < 4; ++i)
#pragma unroll
    for (int j = 0; j < 4; ++j)
#pragma unroll
      for (int r = 0; r < 4; ++r)
        sm.s_tile[(8 + wm + i * 16 + quad * 4 + r) * 129 + wn + j * 16 + l15] = acc[i][j][r];
  __syncthreads();

  // ---- windowed scan: 256 threads = 128 cols x 2 half-chunks of 64 rows ----
  const int col = tid & 127;
  const int half = tid >> 7;
  const float aj = a_mat[bn * 128 + col];
  float h = 0.0f;
  const int row0 = 8 + half * 64;
  if (!(bm == 0 && half == 0)) {
#pragma unroll
    for (int r = row0 - 8; r < row0; ++r)  // warm-up (discarded outputs)
      h = tanh_fast(fmaf(aj, h, sm.s_tile[r * 129 + col]));
  }
  const size_t gbase = (size_t)(bm * 128 + half * 64) * Hdim + bn * 128 + col;
#pragma unroll 4
  for (int r2 = 0; r2 < 64; ++r2) {
    h = tanh_fast(fmaf(aj, h, sm.s_tile[(row0 + r2) * 129 + col]));
    out[gbase + (size_t)r2 * Hdim] = h;
  }
}

extern "C" void kernel_launch(void* const* d_in, const int* in_sizes, int n_in,
                              void* d_out, int out_size, void* d_ws, size_t ws_size,
                              hipStream_t stream) {
  const float* x = (const float*)d_in[0];
  const float* a = (const float*)d_in[1];
  const float* b = (const float*)d_in[2];
  float* out = (float*)d_out;

  unsigned short* ws = (unsigned short*)d_ws;
  unsigned short* xbf = ws;                                 // 16.8 MB
  unsigned short* btb = xbf + (size_t)Tdim * Hdim;          // 8.4 MB

  hipLaunchKernelGGL(cvt_kernel, dim3(4096 + (Hdim / 64) * (Hdim / 64)), dim3(256), 0, stream,
                     x, b, xbf, btb);
  // grid: x = bm (32, fastest -> XCD = bm%8), y = bn (16)
  hipLaunchKernelGGL(gemm_scan_kernel, dim3(Tdim / 128, Hdim / 128), dim3(256), 0, stream,
                     xbf, btb, a, out);
}